// Round 1
// 12176.769 us; speedup vs baseline: 2.6481x; 2.6481x over previous
//
#include <hip/hip_runtime.h>

typedef unsigned short u16;
typedef unsigned int u32;
typedef unsigned long long u64;
typedef __attribute__((ext_vector_type(8))) short short8;
typedef __attribute__((ext_vector_type(4))) float f32x4;
typedef __attribute__((ext_vector_type(4))) float f4v;
typedef __attribute__((ext_vector_type(4))) unsigned short us4v;

#define TT 512
#define BB_ 32
#define II 2048
#define HH 1024

__device__ __forceinline__ u16 f2bf(float f) {
    u32 u = __float_as_uint(f);
    return (u16)((u + 0x7fffu + ((u >> 16) & 1u)) >> 16);
}
__device__ __forceinline__ float bf2f(u16 h) {
    return __uint_as_float(((u32)h) << 16);
}
__device__ __forceinline__ float ftanh(float x) {
    float e = __expf(2.f * x);
    return 1.f - 2.f / (e + 1.f);
}

// ---------------- fp32 -> bf16 conversion ----------------
__global__ __launch_bounds__(256) void f2bf_k(const float* __restrict__ s,
                                              u16* __restrict__ d, int n) {
    int i = (blockIdx.x * 256 + threadIdx.x) * 4;
    int stride = gridDim.x * 1024;
    for (; i < n; i += stride) {
        f4v v = *(const f4v*)(s + i);
        us4v o;
        o.x = f2bf(v.x); o.y = f2bf(v.y); o.z = f2bf(v.z); o.w = f2bf(v.w);
        *(us4v*)(d + i) = o;
    }
}

// ---------------- lens + flag init (dtype-robust mask read) ----------------
__global__ void prep(const unsigned char* __restrict__ mb, int* __restrict__ lens,
                     int* __restrict__ bar) {
    __shared__ int is8;
    int t = threadIdx.x;
    if (t == 0) is8 = 0;
    __syncthreads();
    for (int i = t; i < TT * BB_; i += 256) {
        if ((i & 3) && mb[i]) is8 = 1;   // benign race, same value
    }
    __syncthreads();
    int u8 = is8;
    if (t < BB_) {
        int c = 0;
        if (u8) {
            const unsigned char* r = mb + t * TT;
            for (int k = 0; k < TT; ++k) c += (r[k] == 0);
        } else {
            const int* r = (const int*)mb + t * TT;
            for (int k = 0; k < TT; ++k) c += (r[k] == 0);
        }
        c = (c < 0) ? 0 : (c > TT ? TT : c);
        lens[t] = c;
    }
    // zero 256 flag slots, each padded to 32 ints (128 B)
    for (int i = t; i < 256 * 32; i += 256) bar[i] = 0;
}

// ---------------- GEMM: G[m,n] = X[m,:] . W[n,:] + bi[n] + bh[n] ----------------
#define GM 16384
#define GN 4096
#define GK 2048

__device__ __forceinline__ void gload_lds16(const u16* g, u16* l) {
    __builtin_amdgcn_global_load_lds(
        (const __attribute__((address_space(1))) void*)g,
        (__attribute__((address_space(3))) void*)l, 16, 0, 0);
}

__global__ __launch_bounds__(256) void gemm_xw(
    const u16* __restrict__ X, const u16* __restrict__ W,
    const float* __restrict__ bi, const float* __restrict__ bh,
    u16* __restrict__ G)
{
    __shared__ u16 As[4096];
    __shared__ u16 Bs[4096];
    const int tid  = threadIdx.x;
    const int lane = tid & 63;
    const int r15  = lane & 15;
    const int quad = lane >> 4;
    const int wid  = tid >> 6;
    const int wr   = wid >> 1;
    const int wc   = wid & 1;
    const int m0   = blockIdx.y << 7;
    const int n0   = blockIdx.x << 7;

    f32x4 acc[4][4];
#pragma unroll
    for (int i = 0; i < 4; ++i)
#pragma unroll
        for (int j = 0; j < 4; ++j) acc[i][j] = (f32x4){0.f, 0.f, 0.f, 0.f};

    const int c0 = tid, c1 = 256 + tid;
    const int kq0 = c0 >> 7, row0 = c0 & 127;
    const int kq1 = c1 >> 7, row1 = c1 & 127;

    const u16* xA0 = X + (size_t)(m0 + row0) * GK + kq0 * 8;
    const u16* xA1 = X + (size_t)(m0 + row1) * GK + kq1 * 8;
    const u16* xB0 = W + (size_t)(n0 + row0) * GK + kq0 * 8;
    const u16* xB1 = W + (size_t)(n0 + row1) * GK + kq1 * 8;

    for (int kb = 0; kb < GK; kb += 32) {
        __syncthreads();
        gload_lds16(xA0 + kb, As + c0 * 8);
        gload_lds16(xA1 + kb, As + c1 * 8);
        gload_lds16(xB0 + kb, Bs + c0 * 8);
        gload_lds16(xB1 + kb, Bs + c1 * 8);
        __syncthreads();

        short8 a[4], b[4];
#pragma unroll
        for (int i = 0; i < 4; ++i)
            a[i] = *(const short8*)(As + (quad * 128 + wr * 64 + i * 16 + r15) * 8);
#pragma unroll
        for (int j = 0; j < 4; ++j)
            b[j] = *(const short8*)(Bs + (quad * 128 + wc * 64 + j * 16 + r15) * 8);
#pragma unroll
        for (int i = 0; i < 4; ++i)
#pragma unroll
            for (int j = 0; j < 4; ++j)
                acc[i][j] = __builtin_amdgcn_mfma_f32_16x16x32_bf16(a[i], b[j], acc[i][j], 0, 0, 0);
    }

#pragma unroll
    for (int j = 0; j < 4; ++j) {
        const int col = n0 + wc * 64 + j * 16 + r15;
        const float bias = bi[col] + bh[col];
#pragma unroll
        for (int i = 0; i < 4; ++i) {
            const int row = m0 + wr * 64 + i * 16 + quad * 4;
#pragma unroll
            for (int r = 0; r < 4; ++r)
                G[(size_t)(row + r) * GN + col] = f2bf(acc[i][j][r] + bias);
        }
    }
}

// ---------------- persistent LSTM layer (cooperative) ----------------
// Sync protocol: per-block monotonic flag (padded to 128 B).  flag == pbase+s+1
// means "this block's h_s is at the coherent point".  h is exchanged with
// relaxed AGENT-scope (write-through sc1) atomic stores/loads, so NO
// buffer_wbl2 / buffer_inv / contended RMW appears anywhere in the loop.
#define NBLK 256

#define LOADC(dst, basef)                                                          \
  { _Pragma("unroll")                                                              \
    for (int f = 0; f < 8; ++f) {                                                  \
      const u64* hq = (const u64*)(hb + ((basef) + f) * 32 + quad * 8);            \
      union { u64 q[2]; short8 v; } uu;                                            \
      uu.q[0] = __hip_atomic_load(hq,     __ATOMIC_RELAXED, __HIP_MEMORY_SCOPE_AGENT); \
      uu.q[1] = __hip_atomic_load(hq + 1, __ATOMIC_RELAXED, __HIP_MEMORY_SCOPE_AGENT); \
      dst[f] = uu.v;                                                               \
    } }

#define MFMA8(src, basef)                                                          \
  { _Pragma("unroll")                                                              \
    for (int f = 0; f < 8; ++f)                                                    \
      acc[((basef) + f) & 3] = __builtin_amdgcn_mfma_f32_16x16x32_bf16(            \
          src[f], Bf[(basef) + f], acc[((basef) + f) & 3], 0, 0, 0);               \
  }

__global__ __launch_bounds__(256, 1) void lstm_layer(
    int layer, int pbase,
    const u16* __restrict__ Whh,   // [4][4096][1024] bf16
    const u16* __restrict__ Gf,    // [16384][4096] bf16
    const u16* __restrict__ Gb,
    u16* __restrict__ ys0,         // layer0 output bf16 [16384][2048]
    float* __restrict__ out,       // d_out
    u16* __restrict__ hbuf,        // [2 buf][2 dir][32][1024] bf16
    const int* __restrict__ lens,
    int* __restrict__ bar)         // 256 flag slots * 32 ints
{
    const int blk   = blockIdx.x;
    const int dir   = blk & 1;
    const int slice = blk >> 1;     // 0..127
    const int j0    = slice << 3;   // 8 h-units per block
    const int tid   = threadIdx.x;
    const int lane  = tid & 63;
    const int r15   = lane & 15;
    const int quad  = lane >> 4;
    const int wid   = tid >> 6;
    const int bt    = wid & 1;      // batch tile
    const int rt    = wid >> 1;     // gate-row tile

    __shared__ float ghh[32][33];

    // Whh B-fragments resident in VGPRs for the whole kernel.
    const int nloc = rt * 16 + r15;                         // local gate row 0..31
    const int rowg = ((nloc >> 3) << 10) + j0 + (nloc & 7); // global gate row
    const u16* wp = Whh + ((size_t)(layer * 2 + dir) << 22) + ((size_t)rowg << 10) + quad * 8;
    short8 Bf[32];
#pragma unroll
    for (int f = 0; f < 32; ++f) Bf[f] = *(const short8*)(wp + f * 32);

    const int ub = tid & 7;        // unit within slice
    const int bb = tid >> 3;       // batch 0..31
    const int gu = j0 + ub;        // global h-unit
    const int len_b = lens[bb];
    float hreg = 0.f, creg = 0.f;

    int* myflag   = bar + ((dir << 7) + slice) * 32;
    int* pollflag = bar + ((dir << 7) + (tid & 127)) * 32;

    // zero h_0 (buffer 0) for own units: write-through, then announce
    if ((ub & 1) == 0) {
        u32* hp = (u32*)(hbuf + (((size_t)dir) << 15) + ((size_t)bb << 10) + gu);
        __hip_atomic_store(hp, 0u, __ATOMIC_RELAXED, __HIP_MEMORY_SCOPE_AGENT);
    }
    asm volatile("s_waitcnt vmcnt(0)" ::: "memory");
    __syncthreads();
    if (tid == 0)
        __hip_atomic_store(myflag, pbase + 1, __ATOMIC_RELAXED, __HIP_MEMORY_SCOPE_AGENT);

    const u16* Gd = dir ? Gb : Gf;
    const int abase = (bt * 16 + r15) << 10;

    // prefetch gates for step 0 (s=0 is always valid: len >= 64)
    int pcur = dir ? (len_b - 1) : 0;
    const u16* gp0 = Gd + (((size_t)pcur << 5) + bb) * 4096 + gu;
    u16 gvi = gp0[0], gvf = gp0[1024], gvg = gp0[2048], gvo = gp0[3072];

    for (int s = 0; s < TT; ++s) {
        // wait until every block of this direction has published h_s.
        // 128 threads poll 128 distinct 128B-padded flags: no contention, no inv.
        if (tid < 128) {
            const int target = pbase + s + 1;
            while (__hip_atomic_load(pollflag, __ATOMIC_RELAXED, __HIP_MEMORY_SCOPE_AGENT) < target)
                __builtin_amdgcn_s_sleep(1);
        }
        __syncthreads();

        const u16* hb = hbuf + (((size_t)((s & 1) * 2 + dir)) << 15) + abase;

        f32x4 acc[4];
#pragma unroll
        for (int q2 = 0; q2 < 4; ++q2) acc[q2] = (f32x4){0.f, 0.f, 0.f, 0.f};

        // h-gather (always from coherent point) software-pipelined vs MFMA
        short8 a0[8], a1[8];
        LOADC(a0, 0);
        LOADC(a1, 8);
        MFMA8(a0, 0);
        LOADC(a0, 16);
        MFMA8(a1, 8);
        LOADC(a1, 24);
        MFMA8(a0, 16);
        MFMA8(a1, 24);

        f32x4 ac = (acc[0] + acc[1]) + (acc[2] + acc[3]);
#pragma unroll
        for (int r = 0; r < 4; ++r)
            ghh[bt * 16 + quad * 4 + r][nloc] = ac[r];
        __syncthreads();

        float gi  = ghh[bb][ub]      + bf2f(gvi);
        float gf_ = ghh[bb][8 + ub]  + bf2f(gvf);
        float gg  = ghh[bb][16 + ub] + bf2f(gvg);
        float go  = ghh[bb][24 + ub] + bf2f(gvo);
        float si = 1.f / (1.f + __expf(-gi));
        float sf = 1.f / (1.f + __expf(-gf_));
        float sg = ftanh(gg);
        float so = 1.f / (1.f + __expf(-go));
        float cn = sf * creg + si * sg;
        float hn = so * ftanh(cn);
        bool valid = (s < len_b);
        if (valid) { creg = cn; hreg = hn; }

        // publish h_{s+1}: lane-paired u32, write-through to coherent point
        u32 hv = (u32)f2bf(hreg);
        u32 pv = (u32)__shfl_xor((int)hv, 1);
        if ((ub & 1) == 0) {
            u32 pk = hv | (pv << 16);
            u32* hp = (u32*)(hbuf + (((size_t)(((s + 1) & 1) * 2 + dir)) << 15)
                             + ((size_t)bb << 10) + gu);
            __hip_atomic_store(hp, pk, __ATOMIC_RELAXED, __HIP_MEMORY_SCOPE_AGENT);
        }

        float yv = valid ? hn : 0.f;
        size_t yoff = (((size_t)pcur << 5) + bb) * 2048 + ((size_t)dir << 10) + gu;
        if (layer == 0) ys0[yoff] = f2bf(yv);
        else            out[yoff] = yv;

        asm volatile("s_waitcnt vmcnt(0)" ::: "memory");
        __syncthreads();
        if (tid == 0)
            __hip_atomic_store(myflag, pbase + s + 2, __ATOMIC_RELAXED, __HIP_MEMORY_SCOPE_AGENT);

        // prefetch gates for s+1: in flight during the next poll
        int sn = s + 1;
        if (sn < TT) {
            int pn = dir ? ((sn < len_b) ? (len_b - 1 - sn) : sn) : sn;
            const u16* gp = Gd + (((size_t)pn << 5) + bb) * 4096 + gu;
            gvi = gp[0]; gvf = gp[1024]; gvg = gp[2048]; gvo = gp[3072];
            pcur = pn;
        }
    }

    size_t hoff = (size_t)TT * BB_ * 2048 + (((size_t)(layer * 2 + dir) << 5) + bb) * 1024 + gu;
    out[hoff] = hreg;
    out[hoff + 4 * BB_ * HH] = creg;
}

// ---------------- host ----------------
extern "C" void kernel_launch(void* const* d_in, const int* in_sizes, int n_in,
                              void* d_out, int out_size, void* d_ws, size_t ws_size,
                              hipStream_t stream)
{
    const float* x    = (const float*)d_in[0];
    const unsigned char* mask = (const unsigned char*)d_in[1];
    const float* Wih  = (const float*)d_in[2];
    const float* Whh  = (const float*)d_in[3];
    const float* bih  = (const float*)d_in[4];
    const float* bhh  = (const float*)d_in[5];
    float* out = (float*)d_out;

    char* w = (char*)d_ws;
    size_t off = 0;
    auto take = [&](size_t bytes) {
        char* p = w + off;
        off = (off + bytes + 255) & ~(size_t)255;
        return p;
    };
    u16* xbf    = (u16*)take((size_t)33554432 * 2);   // x bf16; ALIASED as ys0 after layer-0 GEMMs
    u16* ysbf   = xbf;
    u16* wslice = (u16*)take((size_t)8388608 * 2);    // one Wih slice bf16, reused 4x
    u16* whhbf  = (u16*)take((size_t)16777216 * 2);   // Whh bf16
    u16* gf     = (u16*)take((size_t)67108864 * 2);   // gates fwd bf16
    u16* gb     = (u16*)take((size_t)67108864 * 2);   // gates bwd bf16
    u16* hbuf   = (u16*)take((size_t)131072 * 2);
    int* lens   = (int*)take(1024);
    int* bar    = (int*)take(65536);                  // 256 flags * 128 B

    f2bf_k<<<2048, 256, 0, stream>>>(x,   xbf,   33554432);
    f2bf_k<<<2048, 256, 0, stream>>>(Whh, whhbf, 16777216);
    prep<<<1, 256, 0, stream>>>(mask, lens, bar);

    dim3 gg(32, 128);
    for (int l = 0; l < 2; ++l) {
        const u16* X = l ? ysbf : xbf;
        for (int d = 0; d < 2; ++d) {
            f2bf_k<<<1024, 256, 0, stream>>>(Wih + (size_t)(l * 2 + d) * 4096 * 2048,
                                             wslice, 8388608);
            gemm_xw<<<gg, 256, 0, stream>>>(X, wslice,
                                            bih + (l * 2 + d) * 4096,
                                            bhh + (l * 2 + d) * 4096,
                                            d ? gb : gf);
        }
        int layer = l;
        int pbase = l * (TT + 1);
        void* args[] = { &layer, &pbase, (void*)&whhbf, (void*)&gf, (void*)&gb,
                         (void*)&ysbf, (void*)&out, (void*)&hbuf, (void*)&lens, (void*)&bar };
        hipLaunchCooperativeKernel((void*)lstm_layer, dim3(NBLK), dim3(256), args, 0, stream);
    }
    (void)in_sizes; (void)n_in; (void)out_size; (void)ws_size;
}